// Round 3
// baseline (389.420 us; speedup 1.0000x reference)
//
#include <hip/hip_runtime.h>

typedef unsigned short u16;
typedef unsigned int u32;
typedef __attribute__((ext_vector_type(8))) short bfrag_t;   // 8 bf16 (4 VGPRs)
typedef __attribute__((ext_vector_type(4))) float accfrag_t; // 4 fp32

// ---------- bf16 helpers (RNE) ----------
__device__ __forceinline__ u16 f2b(float f) {
    u32 u = __float_as_uint(f);
    u32 r = (u + 0x7FFFu + ((u >> 16) & 1u)) >> 16;
    return (u16)r;
}
__device__ __forceinline__ float b2f(u16 b) {
    return __uint_as_float(((u32)b) << 16);
}

// ---------- async global->LDS, 16B per lane ----------
__device__ __forceinline__ void load16(const u16* g, u16* l) {
    __builtin_amdgcn_global_load_lds(
        (__attribute__((address_space(1))) void*)(u16*)g,
        (__attribute__((address_space(3))) void*)l,
        16, 0, 0);
}

// ============================================================
// x[8,256,56,56] f32 -> x_tp[8,58,58,256] bf16, zero-padded border.
// ============================================================
__global__ __launch_bounds__(256) void k_xtp(const float* __restrict__ x,
                                             u16* __restrict__ xtp) {
    const int bh = blockIdx.x;          // 8*58
    const int b = bh / 58;
    const int hp = bh - b * 58;
    const int tid = threadIdx.x;
    u16* rowbase = xtp + (size_t)(b * 58 + hp) * 58 * 256;
    if (hp == 0 || hp == 57) {
        u32* p = (u32*)rowbase;
        for (int i = tid; i < 58 * 128; i += 256) p[i] = 0;
        return;
    }
    __shared__ float lds[256 * 57];
    const int h = hp - 1;
    const float* xb = x + (size_t)b * 802816 + h * 56;
    for (int idx = tid; idx < 256 * 56; idx += 256) {
        int c = idx / 56;
        int w = idx - c * 56;
        lds[c * 57 + w] = xb[c * 3136 + w];
    }
    __syncthreads();
    rowbase[tid] = 0;
    rowbase[57 * 256 + tid] = 0;
    for (int wp = 1; wp <= 56; ++wp)
        rowbase[wp * 256 + tid] = f2b(lds[tid * 57 + (wp - 1)]);
}

// ============================================================
// Weight prep. K-permutation: d' = rr*256 + c  <->  d = c*9 + rr
// ============================================================
__global__ void k_wt(const float* __restrict__ in, u16* __restrict__ out) {
    // in = W [2304, 256]; out[n][kp] = in[d(kp)][n]   (256 x 2304)
    int idx = blockIdx.x * 256 + threadIdx.x;
    int n = idx / 2304;
    int kp = idx - n * 2304;
    int d = (kp & 255) * 9 + (kp >> 8);
    out[idx] = f2b(in[d * 256 + n]);
}
__global__ void k_w2t(const float* __restrict__ in, u16* __restrict__ out) {
    // in = W2 [256, 2304]; out[np][k] = in[k][d(np)]  (2304 x 256)
    int idx = blockIdx.x * 256 + threadIdx.x;
    int np = idx >> 8;
    int k = idx & 255;
    int d = (np & 255) * 9 + (np >> 8);
    out[idx] = f2b(in[k * 2304 + d]);
}
__global__ void k_b2p(const float* __restrict__ in, float* __restrict__ out) {
    int idx = blockIdx.x * 256 + threadIdx.x;
    if (idx < 2304) out[idx] = in[(idx & 255) * 9 + (idx >> 8)];
}

// ============================================================
// Fully-fused kernel: per 64-row block,
//   phase1 : h1 = relu(t @ W1 + b1)            (h1 -> LDS, K=2304)
//   per rr : z  = h1 @ W2slab + b2'            (K=256)
//            per half: u = t * sigmoid(z)      (-> LDS)
//                      out += u @ W3slab-half  (K=128)
//   epilogue: out += b3 -> global f32
// Wave w owns output cols [w*64, w*64+64) in every phase; m = 64 full.
// ============================================================
__global__ __launch_bounds__(256, 2) void k_fused(
    const u16* __restrict__ xtp, const u16* __restrict__ W1t,
    const u16* __restrict__ W2t, const u16* __restrict__ W3t,
    const float* __restrict__ b1, const float* __restrict__ b2p,
    const float* __restrict__ b3, float* __restrict__ out) {
    __shared__ __align__(16) u16 h1s[64 * 264];  // stride 264 (132dw == 4 mod 32)
    __shared__ __align__(16) u16 us[64 * 136];   // stride 136 (68dw == 4 mod 32)
    __shared__ __align__(16) u16 Bs[256 * 32];   // B-chunk staging, 16KB

    const int tid = threadIdx.x;
    const int wave = tid >> 6;
    const int lane = tid & 63;
    const int fr = lane & 15;
    const int fq = lane >> 4;
    const int srow = lane >> 2;        // 0..15
    const int scol = (lane & 3) * 8;   // 0,8,16,24
    const int l0 = blockIdx.x * 64;
    const int colW = wave * 64;

    // per-thread xtp base for phase1 A staging (row = l0 + wave*16 + srow)
    int aoff;
    {
        int l = l0 + wave * 16 + srow;
        int b = l / 3136;
        int rem = l - b * 3136;
        int h = rem / 56;
        int w = rem - h * 56;
        aoff = ((b * 58 + h + 1) * 58 + (w + 1)) * 256 + scol;
    }
    // per-thread xtp bases for the vector u-pass (rows tid>>4 + {0,16,32,48})
    int xb4[4];
#pragma unroll
    for (int it = 0; it < 4; ++it) {
        int l = l0 + it * 16 + (tid >> 4);
        int b = l / 3136;
        int rem = l - b * 3136;
        int h = rem / 56;
        int w = rem - h * 56;
        xb4[it] = ((b * 58 + h + 1) * 58 + (w + 1)) * 256;
    }

    accfrag_t acc[4][4];   // phase1 h1-logits, then reused per-rr for z-logits
    accfrag_t accO[4][4];  // out accumulator (whole kernel)
#pragma unroll
    for (int i = 0; i < 4; ++i)
#pragma unroll
        for (int j = 0; j < 4; ++j) {
            acc[i][j] = (accfrag_t)0.f;
            accO[i][j] = (accfrag_t)0.f;
        }

    // ---------------- phase 1: h1 = relu(t @ W1 + b1) ----------------
    for (int rr = 0; rr < 9; ++rr) {
        const int shift = ((rr / 3 - 1) * 58 + (rr % 3) - 1) * 256;
#pragma unroll
        for (int c0 = 0; c0 < 256; c0 += 32) {
            __syncthreads();
            load16(xtp + aoff + shift + c0, us + wave * 512 + lane * 8);
#pragma unroll
            for (int q = 0; q < 4; ++q)
                load16(W1t + (size_t)(q * 64 + wave * 16 + srow) * 2304 +
                           rr * 256 + c0 + scol,
                       Bs + q * 2048 + wave * 512 + lane * 8);
            __syncthreads();
            bfrag_t af[4], bf[4];
#pragma unroll
            for (int i = 0; i < 4; ++i)
                af[i] = *(const bfrag_t*)(us + (i * 16 + fr) * 32 + fq * 8);
#pragma unroll
            for (int j = 0; j < 4; ++j)
                bf[j] = *(const bfrag_t*)(Bs + (colW + j * 16 + fr) * 32 + fq * 8);
#pragma unroll
            for (int i = 0; i < 4; ++i)
#pragma unroll
                for (int j = 0; j < 4; ++j)
                    acc[i][j] = __builtin_amdgcn_mfma_f32_16x16x32_bf16(
                        af[i], bf[j], acc[i][j], 0, 0, 0);
        }
    }
    // epilogue: relu, pair-pack, scatter into h1s (b32 writes, even lanes)
#pragma unroll
    for (int i = 0; i < 4; ++i) {
#pragma unroll
        for (int j = 0; j < 4; ++j) {
            const int col = colW + j * 16 + fr;
            const float bv = b1[col];
#pragma unroll
            for (int r = 0; r < 4; ++r) {
                float v = acc[i][j][r] + bv;
                v = v > 0.f ? v : 0.f;
                float vh = __shfl_down(v, 1);
                if (!(lane & 1)) {
                    u32 pk = (u32)f2b(v) | ((u32)f2b(vh) << 16);
                    *(u32*)&h1s[(i * 16 + fq * 4 + r) * 264 + col] = pk;
                }
            }
        }
    }

    // ---------------- phase 2: per rr slab ----------------
    for (int rr = 0; rr < 9; ++rr) {
        const int shift = ((rr / 3 - 1) * 58 + (rr % 3) - 1) * 256;
        // 2a: z = h1 @ W2slab  (K = 256 over c; A-frags straight from h1s)
#pragma unroll
        for (int i = 0; i < 4; ++i)
#pragma unroll
            for (int j = 0; j < 4; ++j) acc[i][j] = (accfrag_t)0.f;
#pragma unroll
        for (int c0 = 0; c0 < 256; c0 += 32) {
            __syncthreads();
#pragma unroll
            for (int q = 0; q < 4; ++q)
                load16(W2t + (size_t)(rr * 256 + q * 64 + wave * 16 + srow) * 256 +
                           c0 + scol,
                       Bs + q * 2048 + wave * 512 + lane * 8);
            __syncthreads();
            bfrag_t af[4], bf[4];
#pragma unroll
            for (int i = 0; i < 4; ++i)
                af[i] = *(const bfrag_t*)(h1s + (i * 16 + fr) * 264 + c0 + fq * 8);
#pragma unroll
            for (int j = 0; j < 4; ++j)
                bf[j] = *(const bfrag_t*)(Bs + (colW + j * 16 + fr) * 32 + fq * 8);
#pragma unroll
            for (int i = 0; i < 4; ++i)
#pragma unroll
                for (int j = 0; j < 4; ++j)
                    acc[i][j] = __builtin_amdgcn_mfma_f32_16x16x32_bf16(
                        af[i], bf[j], acc[i][j], 0, 0, 0);
        }
        // halves: sigmoid-scatter -> t-multiply -> GEMM3 accumulate
#pragma unroll
        for (int h = 0; h < 2; ++h) {
            __syncthreads();  // prior us readers done
            if ((wave >> 1) == h) {
                const int colh0 = (wave & 1) * 64;
#pragma unroll
                for (int i = 0; i < 4; ++i) {
#pragma unroll
                    for (int j = 0; j < 4; ++j) {
                        const int colh = colh0 + j * 16 + fr;
                        const float bv = b2p[rr * 256 + h * 128 + colh];
#pragma unroll
                        for (int r = 0; r < 4; ++r) {
                            const float z = acc[i][j][r] + bv;
                            const float s = 1.f / (1.f + __expf(-z));
                            const float sh = __shfl_down(s, 1);
                            if (!(lane & 1)) {
                                u32 pk = (u32)f2b(s) | ((u32)f2b(sh) << 16);
                                *(u32*)&us[(i * 16 + fq * 4 + r) * 136 + colh] = pk;
                            }
                        }
                    }
                }
            }
            __syncthreads();  // s visible
            // u = t * s  (in place, 16B vector ops; each chunk owned by 1 thread)
#pragma unroll
            for (int it = 0; it < 4; ++it) {
                const int rowl = it * 16 + (tid >> 4);
                const int c8 = (tid & 15) * 8;
                bfrag_t sv = *(const bfrag_t*)(us + rowl * 136 + c8);
                bfrag_t tv = *(const bfrag_t*)(xtp + xb4[it] + shift + h * 128 + c8);
                bfrag_t rv;
#pragma unroll
                for (int e = 0; e < 8; ++e)
                    rv[e] = (short)f2b(b2f((u16)sv[e]) * b2f((u16)tv[e]));
                *(bfrag_t*)(us + rowl * 136 + c8) = rv;
            }
            // 2b: out += u @ W3slab-half  (K = 128)
#pragma unroll
            for (int k0 = 0; k0 < 128; k0 += 32) {
                __syncthreads();
#pragma unroll
                for (int q = 0; q < 4; ++q)
                    load16(W3t + (size_t)(q * 64 + wave * 16 + srow) * 2304 +
                               rr * 256 + h * 128 + k0 + scol,
                           Bs + q * 2048 + wave * 512 + lane * 8);
                __syncthreads();
                bfrag_t af[4], bf[4];
#pragma unroll
                for (int i = 0; i < 4; ++i)
                    af[i] = *(const bfrag_t*)(us + (i * 16 + fr) * 136 + k0 + fq * 8);
#pragma unroll
                for (int j = 0; j < 4; ++j)
                    bf[j] = *(const bfrag_t*)(Bs + (colW + j * 16 + fr) * 32 + fq * 8);
#pragma unroll
                for (int i = 0; i < 4; ++i)
#pragma unroll
                    for (int j = 0; j < 4; ++j)
                        accO[i][j] = __builtin_amdgcn_mfma_f32_16x16x32_bf16(
                            af[i], bf[j], accO[i][j], 0, 0, 0);
            }
        }
    }

    // ---------------- final epilogue: out = accO + b3 (f32, paired stores) ----
#pragma unroll
    for (int i = 0; i < 4; ++i) {
#pragma unroll
        for (int j = 0; j < 4; ++j) {
            const int col = colW + j * 16 + fr;
            const float bv = b3[col];
#pragma unroll
            for (int r = 0; r < 4; ++r) {
                const float v = accO[i][j][r] + bv;
                const float vh = __shfl_down(v, 1);
                if (!(lane & 1)) {
                    float2 st = make_float2(v, vh);
                    *(float2*)(out + (size_t)(l0 + i * 16 + fq * 4 + r) * 256 + col) = st;
                }
            }
        }
    }
}

extern "C" void kernel_launch(void* const* d_in, const int* in_sizes, int n_in,
                              void* d_out, int out_size, void* d_ws, size_t ws_size,
                              hipStream_t stream) {
    const float* x  = (const float*)d_in[0];
    const float* W1 = (const float*)d_in[1];
    const float* b1 = (const float*)d_in[2];
    const float* W2 = (const float*)d_in[3];
    const float* b2 = (const float*)d_in[4];
    const float* W3 = (const float*)d_in[5];
    const float* b3 = (const float*)d_in[6];
    float* out = (float*)d_out;

    // ws: xtp 13.78MB + 3 weights (1.18MB each) + b2p
    char* ws = (char*)d_ws;
    u16* xtp  = (u16*)ws;  ws += (size_t)8 * 58 * 58 * 256 * 2;
    u16* W1t  = (u16*)ws;  ws += (size_t)256 * 2304 * 2;
    u16* W2t  = (u16*)ws;  ws += (size_t)256 * 2304 * 2;
    u16* W3t  = (u16*)ws;  ws += (size_t)256 * 2304 * 2;
    float* b2p = (float*)ws;

    k_wt<<<2304, 256, 0, stream>>>(W1, W1t);
    k_wt<<<2304, 256, 0, stream>>>(W3, W3t);
    k_w2t<<<2304, 256, 0, stream>>>(W2, W2t);
    k_b2p<<<9, 256, 0, stream>>>(b2, b2p);
    k_xtp<<<464, 256, 0, stream>>>(x, xtp);
    k_fused<<<392, 256, 0, stream>>>(xtp, W1t, W2t, W3t, b1, b2p, b3, out);
}

// Round 4
// 279.156 us; speedup vs baseline: 1.3950x; 1.3950x over previous
//
#include <hip/hip_runtime.h>

typedef unsigned short u16;
typedef unsigned int u32;
typedef __attribute__((ext_vector_type(8))) short bfrag_t;   // 8 bf16 (4 VGPRs)
typedef __attribute__((ext_vector_type(4))) float accfrag_t; // 4 fp32

// ---------- bf16 helpers (RNE) ----------
__device__ __forceinline__ u16 f2b(float f) {
    u32 u = __float_as_uint(f);
    u32 r = (u + 0x7FFFu + ((u >> 16) & 1u)) >> 16;
    return (u16)r;
}
__device__ __forceinline__ float b2f(u16 b) {
    return __uint_as_float(((u32)b) << 16);
}

// ---------- async global->LDS, 16B per lane ----------
__device__ __forceinline__ void load16(const u16* g, u16* l) {
    __builtin_amdgcn_global_load_lds(
        (__attribute__((address_space(1))) void*)(u16*)g,
        (__attribute__((address_space(3))) void*)l,
        16, 0, 0);
}

// ============================================================
// x[8,256,56,56] f32 -> x_tp[8,58,58,256] bf16, zero-padded border.
// ============================================================
__global__ __launch_bounds__(256) void k_xtp(const float* __restrict__ x,
                                             u16* __restrict__ xtp) {
    const int bh = blockIdx.x;          // 8*58
    const int b = bh / 58;
    const int hp = bh - b * 58;
    const int tid = threadIdx.x;
    u16* rowbase = xtp + (size_t)(b * 58 + hp) * 58 * 256;
    if (hp == 0 || hp == 57) {
        u32* p = (u32*)rowbase;
        for (int i = tid; i < 58 * 128; i += 256) p[i] = 0;
        return;
    }
    __shared__ float lds[256 * 57];
    const int h = hp - 1;
    const float* xb = x + (size_t)b * 802816 + h * 56;
    for (int idx = tid; idx < 256 * 56; idx += 256) {
        int c = idx / 56;
        int w = idx - c * 56;
        lds[c * 57 + w] = xb[c * 3136 + w];
    }
    __syncthreads();
    rowbase[tid] = 0;
    rowbase[57 * 256 + tid] = 0;
    for (int wp = 1; wp <= 56; ++wp)
        rowbase[wp * 256 + tid] = f2b(lds[tid * 57 + (wp - 1)]);
}

// ============================================================
// Weight packs into MFMA-B-fragment-linear order.
// d' = rr*256 + c  <->  d = c*9 + rr  (K/N permutation of the 2304 dim)
//
// W1f/W3f (in: W[2304,256]):  layout [w:4][kc72:72][j:4][lane:64][e:8]
//   n = w*64 + j*16 + (lane&15); kp = kc72*32 + (lane>>4)*8 + e
//   val = W[d(kp)][n]
// ============================================================
__global__ void k_wpack13(const float* __restrict__ in, u16* __restrict__ out) {
    int idx = blockIdx.x * 256 + threadIdx.x;   // 589824 total
    int e = idx & 7;
    int lane = (idx >> 3) & 63;
    int j = (idx >> 9) & 3;
    int g = idx >> 11;            // 0..287 = w*72 + kc72
    int w = g / 72;
    int kc = g - w * 72;
    int n = w * 64 + j * 16 + (lane & 15);
    int kp = kc * 32 + (lane >> 4) * 8 + e;
    int d = (kp & 255) * 9 + (kp >> 8);
    out[idx] = f2b(in[d * 256 + n]);
}
// W2f (in: W2[256,2304]): layout [rr:9][w:4][kc:8][j:4][lane:64][e:8]
//   col_slab = (j>>1)*128 + w*32 + (j&1)*16 + (lane&15)
//   np = rr*256 + col_slab ; k = kc*32 + (lane>>4)*8 + e ; val = W2[k][d(np)]
__global__ void k_wpack2(const float* __restrict__ in, u16* __restrict__ out) {
    int idx = blockIdx.x * 256 + threadIdx.x;   // 589824 total
    int e = idx & 7;
    int lane = (idx >> 3) & 63;
    int j = (idx >> 9) & 3;
    int kc = (idx >> 11) & 7;
    int g = idx >> 14;            // 0..35 = rr*4 + w
    int rr = g >> 2;
    int w = g & 3;
    int col = (j >> 1) * 128 + w * 32 + (j & 1) * 16 + (lane & 15);
    int np = rr * 256 + col;
    int d = (np & 255) * 9 + (np >> 8);
    int k = kc * 32 + (lane >> 4) * 8 + e;
    out[idx] = f2b(in[k * 2304 + d]);
}
__global__ void k_b2p(const float* __restrict__ in, float* __restrict__ out) {
    int idx = blockIdx.x * 256 + threadIdx.x;
    if (idx < 2304) out[idx] = in[(idx & 255) * 9 + (idx >> 8)];
}

// ============================================================
// Fused kernel, restructured K-loop:
//  - B-frags: direct coalesced 16B global loads from frag-packed weights
//    (L2-resident) -> no B staging, no per-chunk barriers.
//  - phase1 A: whole 64x256 rr-slab staged via 8x load16 -> 2 barriers/slab.
//  - h1 kept chunk-major in the same 32KB arena, read barrier-free in 2a.
//  - us half-buffer 16KB; 3 barriers per half for sigmoid/t-mult/gemm3.
// ============================================================
__global__ __launch_bounds__(256, 2) void k_fused(
    const u16* __restrict__ xtp, const u16* __restrict__ W1f,
    const u16* __restrict__ W2f, const u16* __restrict__ W3f,
    const float* __restrict__ b1, const float* __restrict__ b2p,
    const float* __restrict__ b3, float* __restrict__ out) {
    __shared__ __align__(16) u16 As[16384];  // 32KB: A-slab staging, then h1 [kc:8][row:64][c:32]
    __shared__ __align__(16) u16 Us[8192];   // 16KB: u half [kc:4][row:64][c:32]

    const int tid = threadIdx.x;
    const int wave = tid >> 6;
    const int lane = tid & 63;
    const int fr = lane & 15;
    const int fq = lane >> 4;
    const int srow = lane >> 2;        // 0..15
    const int scol = (lane & 3) * 8;
    const int l0 = blockIdx.x * 64;

    // xtp base for phase-1 staging row (wave*16 + srow)
    int aoff;
    {
        int l = l0 + wave * 16 + srow;
        int b = l / 3136;
        int rem = l - b * 3136;
        int h = rem / 56;
        int w = rem - h * 56;
        aoff = ((b * 58 + h + 1) * 58 + (w + 1)) * 256 + scol;
    }
    // xtp bases for the t-multiply pass (rows it*16 + tid>>4)
    int xb4[4];
#pragma unroll
    for (int it = 0; it < 4; ++it) {
        int l = l0 + it * 16 + (tid >> 4);
        int b = l / 3136;
        int rem = l - b * 3136;
        int h = rem / 56;
        int w = rem - h * 56;
        xb4[it] = ((b * 58 + h + 1) * 58 + (w + 1)) * 256;
    }

    accfrag_t acc[4][4];
#pragma unroll
    for (int i = 0; i < 4; ++i)
#pragma unroll
        for (int j = 0; j < 4; ++j) acc[i][j] = (accfrag_t)0.f;

    // ---------------- phase 1: h1 = relu(t @ W1 + b1) ----------------
    const u16* w1base = W1f + (size_t)wave * 72 * 4 * 512 + lane * 8;
    for (int rr = 0; rr < 9; ++rr) {
        const int shift = ((rr / 3 - 1) * 58 + (rr % 3) - 1) * 256;
        __syncthreads();   // prev slab's MFMA reads done
#pragma unroll
        for (int q = 0; q < 8; ++q)
            load16(xtp + aoff + shift + q * 32, As + q * 2048 + wave * 512 + lane * 8);
        __syncthreads();   // slab visible
#pragma unroll
        for (int kc = 0; kc < 8; ++kc) {
            const u16* wb = w1base + (size_t)((rr * 8 + kc) * 4) * 512;
            bfrag_t bf[4], af[4];
#pragma unroll
            for (int j = 0; j < 4; ++j)
                bf[j] = *(const bfrag_t*)(wb + j * 512);
#pragma unroll
            for (int i = 0; i < 4; ++i)
                af[i] = *(const bfrag_t*)(As + kc * 2048 + (i * 16 + fr) * 32 + fq * 8);
#pragma unroll
            for (int i = 0; i < 4; ++i)
#pragma unroll
                for (int j = 0; j < 4; ++j)
                    acc[i][j] = __builtin_amdgcn_mfma_f32_16x16x32_bf16(
                        af[i], bf[j], acc[i][j], 0, 0, 0);
        }
    }
    // h1 epilogue: relu, pair-pack, store chunk-major into As arena
    __syncthreads();
#pragma unroll
    for (int i = 0; i < 4; ++i) {
#pragma unroll
        for (int j = 0; j < 4; ++j) {
            const int col = wave * 64 + j * 16 + fr;
            const float bv = b1[col];
#pragma unroll
            for (int r = 0; r < 4; ++r) {
                float v = acc[i][j][r] + bv;
                v = v > 0.f ? v : 0.f;
                const float vh = __shfl_down(v, 1);
                if (!(lane & 1)) {
                    u32 pk = (u32)f2b(v) | ((u32)f2b(vh) << 16);
                    *(u32*)&As[(col >> 5) * 2048 + (i * 16 + fq * 4 + r) * 32 + (col & 31)] = pk;
                }
            }
        }
    }
    __syncthreads();

    accfrag_t accO[4][4];
#pragma unroll
    for (int i = 0; i < 4; ++i)
#pragma unroll
        for (int j = 0; j < 4; ++j) accO[i][j] = (accfrag_t)0.f;

    // ---------------- phase 2: per rr slab ----------------
    const u16* w3base = W3f + (size_t)wave * 72 * 4 * 512 + lane * 8;
    for (int rr = 0; rr < 9; ++rr) {
        const int shift = ((rr / 3 - 1) * 58 + (rr % 3) - 1) * 256;
        // 2a: z = h1 @ W2slab (K=256, A from As; no barriers)
#pragma unroll
        for (int i = 0; i < 4; ++i)
#pragma unroll
            for (int j = 0; j < 4; ++j) acc[i][j] = (accfrag_t)0.f;
        const u16* w2base = W2f + (size_t)((rr * 4 + wave) * 8) * 4 * 512 + lane * 8;
#pragma unroll
        for (int kc = 0; kc < 8; ++kc) {
            bfrag_t bf[4], af[4];
#pragma unroll
            for (int j = 0; j < 4; ++j)
                bf[j] = *(const bfrag_t*)(w2base + (size_t)(kc * 4 + j) * 512);
#pragma unroll
            for (int i = 0; i < 4; ++i)
                af[i] = *(const bfrag_t*)(As + kc * 2048 + (i * 16 + fr) * 32 + fq * 8);
#pragma unroll
            for (int i = 0; i < 4; ++i)
#pragma unroll
                for (int j = 0; j < 4; ++j)
                    acc[i][j] = __builtin_amdgcn_mfma_f32_16x16x32_bf16(
                        af[i], bf[j], acc[i][j], 0, 0, 0);
        }
        // halves
#pragma unroll
        for (int h = 0; h < 2; ++h) {
            __syncthreads();  // prev-half GEMM3 reads of Us done
            // sigmoid pair-pack -> Us (all 4 waves; j = 2h+jj owns col w*32+jj*16+fr)
#pragma unroll
            for (int i = 0; i < 4; ++i) {
#pragma unroll
                for (int jj = 0; jj < 2; ++jj) {
                    const int j = 2 * h + jj;
                    const int colh = wave * 32 + jj * 16 + fr;
                    const float bv = b2p[rr * 256 + h * 128 + colh];
#pragma unroll
                    for (int r = 0; r < 4; ++r) {
                        const float z = acc[i][j][r] + bv;
                        const float s = 1.f / (1.f + __expf(-z));
                        const float sh = __shfl_down(s, 1);
                        if (!(lane & 1)) {
                            u32 pk = (u32)f2b(s) | ((u32)f2b(sh) << 16);
                            *(u32*)&Us[wave * 2048 + (i * 16 + fq * 4 + r) * 32 + (colh & 31)] = pk;
                        }
                    }
                }
            }
            __syncthreads();  // s visible
            // u = t * s (in-place, 16B vector ops)
#pragma unroll
            for (int it = 0; it < 4; ++it) {
                const int rowl = it * 16 + (tid >> 4);
                const int c8 = (tid & 15) * 8;
                u16* up = Us + (c8 >> 5) * 2048 + rowl * 32 + (c8 & 31);
                bfrag_t sv = *(const bfrag_t*)up;
                bfrag_t tv = *(const bfrag_t*)(xtp + xb4[it] + shift + h * 128 + c8);
                bfrag_t rv;
#pragma unroll
                for (int e = 0; e < 8; ++e)
                    rv[e] = (short)f2b(b2f((u16)sv[e]) * b2f((u16)tv[e]));
                *(bfrag_t*)up = rv;
            }
            __syncthreads();  // u visible
            // 2b: out += u @ W3slab-half (K=128)
#pragma unroll
            for (int kc = 0; kc < 4; ++kc) {
                const u16* wb = w3base + (size_t)((rr * 8 + h * 4 + kc) * 4) * 512;
                bfrag_t bf[4], af[4];
#pragma unroll
                for (int j = 0; j < 4; ++j)
                    bf[j] = *(const bfrag_t*)(wb + j * 512);
#pragma unroll
                for (int i = 0; i < 4; ++i)
                    af[i] = *(const bfrag_t*)(Us + kc * 2048 + (i * 16 + fr) * 32 + fq * 8);
#pragma unroll
                for (int i = 0; i < 4; ++i)
#pragma unroll
                    for (int j = 0; j < 4; ++j)
                        accO[i][j] = __builtin_amdgcn_mfma_f32_16x16x32_bf16(
                            af[i], bf[j], accO[i][j], 0, 0, 0);
            }
        }
    }

    // ---------------- final epilogue: out = accO + b3 ----------------
#pragma unroll
    for (int i = 0; i < 4; ++i) {
#pragma unroll
        for (int j = 0; j < 4; ++j) {
            const int col = wave * 64 + j * 16 + fr;
            const float bv = b3[col];
#pragma unroll
            for (int r = 0; r < 4; ++r) {
                const float v = accO[i][j][r] + bv;
                const float vh = __shfl_down(v, 1);
                if (!(lane & 1)) {
                    float2 st = make_float2(v, vh);
                    *(float2*)(out + (size_t)(l0 + i * 16 + fq * 4 + r) * 256 + col) = st;
                }
            }
        }
    }
}

extern "C" void kernel_launch(void* const* d_in, const int* in_sizes, int n_in,
                              void* d_out, int out_size, void* d_ws, size_t ws_size,
                              hipStream_t stream) {
    const float* x  = (const float*)d_in[0];
    const float* W1 = (const float*)d_in[1];
    const float* b1 = (const float*)d_in[2];
    const float* W2 = (const float*)d_in[3];
    const float* b2 = (const float*)d_in[4];
    const float* W3 = (const float*)d_in[5];
    const float* b3 = (const float*)d_in[6];
    float* out = (float*)d_out;

    char* ws = (char*)d_ws;
    u16* xtp = (u16*)ws;  ws += (size_t)8 * 58 * 58 * 256 * 2;
    u16* W1f = (u16*)ws;  ws += (size_t)589824 * 2;
    u16* W2f = (u16*)ws;  ws += (size_t)589824 * 2;
    u16* W3f = (u16*)ws;  ws += (size_t)589824 * 2;
    float* b2p = (float*)ws;

    k_wpack13<<<2304, 256, 0, stream>>>(W1, W1f);
    k_wpack13<<<2304, 256, 0, stream>>>(W3, W3f);
    k_wpack2<<<2304, 256, 0, stream>>>(W2, W2f);
    k_b2p<<<9, 256, 0, stream>>>(b2, b2p);
    k_xtp<<<464, 256, 0, stream>>>(x, xtp);
    k_fused<<<392, 256, 0, stream>>>(xtp, W1f, W2f, W3f, b1, b2p, b3, out);
}